// Round 5
// baseline (236.989 us; speedup 1.0000x reference)
//
#include <hip/hip_runtime.h>
#include <math.h>

#define BTOT   32768
#define LAT    128
#define H      17
#define G4     68      // 4*H
#define TSTEPS 50
#define NPR    102     // projection rows: 68 (W_ih) + 17 (W_h0) + 17 (W_c0)

#define RPB    30      // rows per block
#define TPB    510     // RPB * H

__device__ __forceinline__ float fsigmoid(float x) {
    float e = __expf(-x);
    return __fdividef(1.0f, 1.0f + e);
}
// overflow-safe tanh: |arg| can reach ~50, naive exp(2x) would overflow
__device__ __forceinline__ float ftanhf(float x) {
    float ax = fabsf(x);
    float e = __expf(-2.0f * ax);
    float t = __fdividef(1.0f - e, 1.0f + e);
    return copysignf(t, x);
}

// Single fused kernel: per block, 30 rows. Phase 1 computes h0/c0/xg for the
// block's rows from x (weights staged in LDS in two k-halves). Phase 2 runs the
// 50-step recurrence with W_hh slices in registers and the h-vector exchanged
// through a double-buffered LDS buffer (1 barrier/step).
// ZERO workspace: eliminates the d_ws interface entirely.
__global__ __launch_bounds__(512, 1)
void lstm_fused(const float* __restrict__ x,
                const float* __restrict__ W_h0, const float* __restrict__ b_h0,
                const float* __restrict__ W_c0, const float* __restrict__ b_c0,
                const float* __restrict__ W_ih, const float* __restrict__ W_hh,
                const float* __restrict__ b_ih, const float* __restrict__ b_hh,
                float* __restrict__ out)
{
    __shared__ float x_tile[RPB][132];     // 15.8 KB (pad 132: +4-bank shift/row)
    __shared__ float Wbuf[NPR][68];        // 27.7 KB (one k-half of all proj weights)
    __shared__ float Wl[G4 * H];           //  4.6 KB (W_hh, persistent)
    __shared__ float hbuf[2][RPB][20];     //  4.8 KB (rows padded to 20 floats)

    const int t = threadIdx.x;
    const int r = t / H;          // local row 0..29
    const int j = t - r * H;      // element 0..16
    const int grow0 = blockIdx.x * RPB;
    int grow = grow0 + r;
    const bool valid = grow < BTOT;
    if (!valid) grow = BTOT - 1;  // masked threads duplicate a row, skip stores

    // ---- stage x tile (rows clamped) + W_hh ----
    for (int i = t; i < RPB * 32; i += TPB) {          // 32 float4 per row
        int rr = i >> 5, c = i & 31;
        int gr = grow0 + rr; if (gr >= BTOT) gr = BTOT - 1;
        float4 v = ((const float4*)(x + (size_t)gr * LAT))[c];
        *(float4*)&x_tile[rr][c * 4] = v;
    }
    for (int i = t; i < G4 * H; i += TPB) Wl[i] = W_hh[i];

    // ---- phase 1: projections, two k-halves of 64 ----
    float acc[6] = {0.f, 0.f, 0.f, 0.f, 0.f, 0.f};     // i,f,g,o, h0, c0
    for (int kh = 0; kh < 2; ++kh) {
        __syncthreads();  // kh=0: x_tile/Wl ready; kh=1: WAR on Wbuf (prev reads done)
        for (int i = t; i < NPR * 16; i += TPB) {      // 16 float4 per half-row
            int row = i >> 4, c = i & 15;
            const float* src = (row < G4) ? (W_ih + row * LAT)
                             : (row < 85) ? (W_h0 + (row - G4) * LAT)
                                          : (W_c0 + (row - 85) * LAT);
            float4 v = ((const float4*)(src + kh * 64))[c];
            *(float4*)&Wbuf[row][c * 4] = v;
        }
        __syncthreads();  // Wbuf half ready

        const int rows[6] = { j, 17 + j, 34 + j, 51 + j, 68 + j, 85 + j };
        for (int kb = 0; kb < 16; ++kb) {
            float4 xv = *(const float4*)&x_tile[r][kh * 64 + kb * 4];
#pragma unroll
            for (int s = 0; s < 6; ++s) {
                float4 wv = *(const float4*)&Wbuf[rows[s]][kb * 4];
                acc[s] = fmaf(xv.x, wv.x, acc[s]);
                acc[s] = fmaf(xv.y, wv.y, acc[s]);
                acc[s] = fmaf(xv.z, wv.z, acc[s]);
                acc[s] = fmaf(xv.w, wv.w, acc[s]);
            }
        }
    }

    const float xgi = acc[0] + b_ih[j]      + b_hh[j];
    const float xgf = acc[1] + b_ih[17 + j] + b_hh[17 + j];
    const float xgg = acc[2] + b_ih[34 + j] + b_hh[34 + j];
    const float xgo = acc[3] + b_ih[51 + j] + b_hh[51 + j];
    float h = acc[4] + b_h0[j];
    float c = acc[5] + b_c0[j];

    // ---- W_hh rows for gates i,f,g,o of element j -> registers ----
    float Wi[H], Wf[H], Wg[H], Wo[H];
#pragma unroll
    for (int k = 0; k < H; ++k) {
        Wi[k] = Wl[(0 * H + j) * H + k];
        Wf[k] = Wl[(1 * H + j) * H + k];
        Wg[k] = Wl[(2 * H + j) * H + k];
        Wo[k] = Wl[(3 * H + j) * H + k];
    }

    // ---- phase 2: 50-step recurrence ----
    float* orow = out + (size_t)grow * (TSTEPS * H) + j;
    int p = 0;
    for (int tt = 0; tt < TSTEPS; ++tt) {
        hbuf[p][r][j] = h;
        __syncthreads();   // single barrier/step: double buffer covers WAR

        float ai = xgi, af = xgf, ag = xgg, ao = xgo;
#pragma unroll
        for (int q = 0; q < 4; ++q) {
            float4 h4 = *(const float4*)&hbuf[p][r][q * 4];  // row-group broadcast
            ai = fmaf(Wi[q * 4 + 0], h4.x, ai);
            af = fmaf(Wf[q * 4 + 0], h4.x, af);
            ag = fmaf(Wg[q * 4 + 0], h4.x, ag);
            ao = fmaf(Wo[q * 4 + 0], h4.x, ao);
            ai = fmaf(Wi[q * 4 + 1], h4.y, ai);
            af = fmaf(Wf[q * 4 + 1], h4.y, af);
            ag = fmaf(Wg[q * 4 + 1], h4.y, ag);
            ao = fmaf(Wo[q * 4 + 1], h4.y, ao);
            ai = fmaf(Wi[q * 4 + 2], h4.z, ai);
            af = fmaf(Wf[q * 4 + 2], h4.z, af);
            ag = fmaf(Wg[q * 4 + 2], h4.z, ag);
            ao = fmaf(Wo[q * 4 + 2], h4.z, ao);
            ai = fmaf(Wi[q * 4 + 3], h4.w, ai);
            af = fmaf(Wf[q * 4 + 3], h4.w, af);
            ag = fmaf(Wg[q * 4 + 3], h4.w, ag);
            ao = fmaf(Wo[q * 4 + 3], h4.w, ao);
        }
        {
            const float hk = hbuf[p][r][16];
            ai = fmaf(Wi[16], hk, ai);
            af = fmaf(Wf[16], hk, af);
            ag = fmaf(Wg[16], hk, ag);
            ao = fmaf(Wo[16], hk, ao);
        }

        const float ig = fsigmoid(ai);
        const float fg = fsigmoid(af);
        const float gv = ftanhf(ag);
        const float og = fsigmoid(ao);
        c = fmaf(fg, c, ig * gv);
        h = og * ftanhf(c);

        if (valid) orow[tt * H] = h;
        p ^= 1;
    }
}

extern "C" void kernel_launch(void* const* d_in, const int* in_sizes, int n_in,
                              void* d_out, int out_size, void* d_ws, size_t ws_size,
                              hipStream_t stream)
{
    const float* x    = (const float*)d_in[0];
    const float* W_h0 = (const float*)d_in[1];
    const float* b_h0 = (const float*)d_in[2];
    const float* W_c0 = (const float*)d_in[3];
    const float* b_c0 = (const float*)d_in[4];
    const float* W_ih = (const float*)d_in[5];
    const float* W_hh = (const float*)d_in[6];
    const float* b_ih = (const float*)d_in[7];
    const float* b_hh = (const float*)d_in[8];
    float* out = (float*)d_out;

    (void)d_ws; (void)ws_size;  // no workspace used

    const int nblk = (BTOT + RPB - 1) / RPB;   // 1093
    hipLaunchKernelGGL(lstm_fused, dim3(nblk), dim3(TPB), 0, stream,
                       x, W_h0, b_h0, W_c0, b_c0, W_ih, W_hh, b_ih, b_hh, out);
}

// Round 6
// 196.851 us; speedup vs baseline: 1.2039x; 1.2039x over previous
//
#include <hip/hip_runtime.h>
#include <math.h>

#define BTOT   32768
#define LAT    128
#define H      17
#define G4     68      // 4*H
#define TSTEPS 50
#define NPR    102     // projection rows: 68 (W_ih) + 17 (W_h0) + 17 (W_c0)
#define WPAD   72      // Wbuf row pad (floats), XOR-swizzled

#define NW     8              // waves per block
#define RPW    3              // rows per wave (51 active lanes of 64)
#define RPB    (NW * RPW)     // 24 rows per block
#define TPB    (NW * 64)      // 512 threads

__device__ __forceinline__ float fsigmoid(float x) {
    float e = __expf(-x);
    return __fdividef(1.0f, 1.0f + e);
}
// overflow-safe tanh: |arg| can reach ~50, naive exp(2x) would overflow
__device__ __forceinline__ float ftanhf(float x) {
    float ax = fabsf(x);
    float e = __expf(-2.0f * ax);
    float t = __fdividef(1.0f - e, 1.0f + e);
    return copysignf(t, x);
}

// Round-5 redesign:
//  - rows are WAVE-LOCAL (3 rows x 17 elems = 51 active lanes/wave) -> the
//    50-step recurrence has ZERO barriers; h is exchanged through a
//    wave-private LDS buffer (compiler orders via lgkmcnt).
//  - W_hh slices pinned into VGPRs via empty asm (round-4 run showed
//    VGPR=68 => compiler was re-reading W from LDS every step).
//  - Wbuf XOR swizzle kills the j/j+8 3-way bank conflict in phase 1.
__global__ __launch_bounds__(TPB, 4)
void lstm_fused(const float* __restrict__ x,
                const float* __restrict__ W_h0, const float* __restrict__ b_h0,
                const float* __restrict__ W_c0, const float* __restrict__ b_c0,
                const float* __restrict__ W_ih, const float* __restrict__ W_hh,
                const float* __restrict__ b_ih, const float* __restrict__ b_hh,
                float* __restrict__ out)
{
    __shared__ float x_tile[RPB][132];      // 12.7 KB
    __shared__ float Wbuf[NPR][WPAD];       // 29.4 KB (one k-half, swizzled)
    __shared__ float Wl[G4 * H];            //  4.6 KB (W_hh)
    __shared__ float hbuf[NW][RPW][20];     //  1.9 KB (wave-private h rows)

    const int t    = threadIdx.x;
    const int w    = t >> 6;
    const int lane = t & 63;
    const bool active = lane < RPW * H;       // 51
    const int rl = active ? (lane / H) : 0;   // 0..2
    const int j  = active ? (lane % H) : 0;   // 0..16
    const int r  = w * RPW + rl;              // 0..23
    const int grow0 = blockIdx.x * RPB;
    int grow = grow0 + r;
    const bool valid = active && (grow < BTOT);
    if (grow >= BTOT) grow = BTOT - 1;

    // ---- stage x tile (rows clamped) + W_hh; all 512 threads ----
    for (int i = t; i < RPB * 32; i += TPB) {              // 32 float4 per row
        int rr = i >> 5, c = i & 31;
        int gr = grow0 + rr; if (gr >= BTOT) gr = BTOT - 1;
        *(float4*)&x_tile[rr][c * 4] = ((const float4*)(x + (size_t)gr * LAT))[c];
    }
    for (int i = t; i < G4 * H; i += TPB) Wl[i] = W_hh[i];

    // ---- phase 1: projections, two k-halves of 64 ----
    float acc[6] = {0.f, 0.f, 0.f, 0.f, 0.f, 0.f};         // i,f,g,o, h0, c0
    for (int kh = 0; kh < 2; ++kh) {
        __syncthreads();  // kh=0: x_tile/Wl ready; kh=1: WAR on Wbuf
        for (int i = t; i < NPR * 16; i += TPB) {          // 16 float4 per half-row
            int row = i >> 4, c4 = (i & 15) * 4;
            const float* src = (row < G4) ? (W_ih + row * LAT)
                             : (row < 85) ? (W_h0 + (row - G4) * LAT)
                                          : (W_c0 + (row - 85) * LAT);
            float4 v = *(const float4*)(src + kh * 64 + c4);
            *(float4*)&Wbuf[row][c4 ^ (((row >> 3) & 1) << 2)] = v;  // swizzled store
        }
        __syncthreads();  // Wbuf half ready

        const int rows6[6] = { j, 17 + j, 34 + j, 51 + j, 68 + j, 85 + j };
        for (int kb = 0; kb < 16; ++kb) {
            float4 xv = *(const float4*)&x_tile[r][kh * 64 + kb * 4];
#pragma unroll
            for (int s = 0; s < 6; ++s) {
                const int row = rows6[s];
                float4 wv = *(const float4*)&Wbuf[row][(kb * 4) ^ (((row >> 3) & 1) << 2)];
                acc[s] = fmaf(xv.x, wv.x, acc[s]);
                acc[s] = fmaf(xv.y, wv.y, acc[s]);
                acc[s] = fmaf(xv.z, wv.z, acc[s]);
                acc[s] = fmaf(xv.w, wv.w, acc[s]);
            }
        }
    }

    const float xgi = acc[0] + b_ih[j]      + b_hh[j];
    const float xgf = acc[1] + b_ih[17 + j] + b_hh[17 + j];
    const float xgg = acc[2] + b_ih[34 + j] + b_hh[34 + j];
    const float xgo = acc[3] + b_ih[51 + j] + b_hh[51 + j];
    float h = acc[4] + b_h0[j];
    float c = acc[5] + b_c0[j];

    // ---- W_hh rows for gates i,f,g,o of element j -> PINNED registers ----
    float Wi[H], Wf[H], Wg[H], Wo[H];
#pragma unroll
    for (int k = 0; k < H; ++k) {
        Wi[k] = Wl[(0 * H + j) * H + k];
        Wf[k] = Wl[(1 * H + j) * H + k];
        Wg[k] = Wl[(2 * H + j) * H + k];
        Wo[k] = Wl[(3 * H + j) * H + k];
        // opaque asm: compiler must materialize in VGPRs, cannot re-read LDS
        asm volatile("" : "+v"(Wi[k]), "+v"(Wf[k]), "+v"(Wg[k]), "+v"(Wo[k]));
    }

    // ---- phase 2: 50-step recurrence, NO barriers (rows are wave-local) ----
    float* orow = out + (size_t)grow * (TSTEPS * H) + j;
    for (int tt = 0; tt < TSTEPS; ++tt) {
        if (active) hbuf[w][rl][j] = h;
        // same-wave write->read on hbuf: compiler inserts lgkmcnt wait

        float ai = xgi, af = xgf, ag = xgg, ao = xgo;
#pragma unroll
        for (int q = 0; q < 4; ++q) {
            float4 h4 = *(const float4*)&hbuf[w][rl][q * 4];
            ai = fmaf(Wi[q * 4 + 0], h4.x, ai);
            af = fmaf(Wf[q * 4 + 0], h4.x, af);
            ag = fmaf(Wg[q * 4 + 0], h4.x, ag);
            ao = fmaf(Wo[q * 4 + 0], h4.x, ao);
            ai = fmaf(Wi[q * 4 + 1], h4.y, ai);
            af = fmaf(Wf[q * 4 + 1], h4.y, af);
            ag = fmaf(Wg[q * 4 + 1], h4.y, ag);
            ao = fmaf(Wo[q * 4 + 1], h4.y, ao);
            ai = fmaf(Wi[q * 4 + 2], h4.z, ai);
            af = fmaf(Wf[q * 4 + 2], h4.z, af);
            ag = fmaf(Wg[q * 4 + 2], h4.z, ag);
            ao = fmaf(Wo[q * 4 + 2], h4.z, ao);
            ai = fmaf(Wi[q * 4 + 3], h4.w, ai);
            af = fmaf(Wf[q * 4 + 3], h4.w, af);
            ag = fmaf(Wg[q * 4 + 3], h4.w, ag);
            ao = fmaf(Wo[q * 4 + 3], h4.w, ao);
        }
        {
            const float hk = hbuf[w][rl][16];
            ai = fmaf(Wi[16], hk, ai);
            af = fmaf(Wf[16], hk, af);
            ag = fmaf(Wg[16], hk, ag);
            ao = fmaf(Wo[16], hk, ao);
        }

        const float ig = fsigmoid(ai);
        const float fg = fsigmoid(af);
        const float gv = ftanhf(ag);
        const float og = fsigmoid(ao);
        c = fmaf(fg, c, ig * gv);
        h = og * ftanhf(c);

        if (valid) orow[tt * H] = h;
    }
}

extern "C" void kernel_launch(void* const* d_in, const int* in_sizes, int n_in,
                              void* d_out, int out_size, void* d_ws, size_t ws_size,
                              hipStream_t stream)
{
    const float* x    = (const float*)d_in[0];
    const float* W_h0 = (const float*)d_in[1];
    const float* b_h0 = (const float*)d_in[2];
    const float* W_c0 = (const float*)d_in[3];
    const float* b_c0 = (const float*)d_in[4];
    const float* W_ih = (const float*)d_in[5];
    const float* W_hh = (const float*)d_in[6];
    const float* b_ih = (const float*)d_in[7];
    const float* b_hh = (const float*)d_in[8];
    float* out = (float*)d_out;

    (void)d_ws; (void)ws_size;  // no workspace used

    const int nblk = (BTOT + RPB - 1) / RPB;   // 1366
    hipLaunchKernelGGL(lstm_fused, dim3(nblk), dim3(TPB), 0, stream,
                       x, W_h0, b_h0, W_c0, b_c0, W_ih, W_hh, b_ih, b_hh, out);
}